// Round 7
// baseline (500.540 us; speedup 1.0000x reference)
//
#include <hip/hip_runtime.h>
#include <hip/hip_bf16.h>

#define N_EDGES 500000
#define N_NODES 50000
#define NT ((N_EDGES + 63) / 64)  // 7813 tiles of 64 edges
#define GRID 512
#define LN_EPS 1e-5f

typedef __attribute__((ext_vector_type(8))) short bf16x8;
typedef __attribute__((ext_vector_type(4))) float f32x4;

static __device__ __forceinline__ short f2bf(float f) {
  return __builtin_bit_cast(short, __float2bfloat16(f));
}
static __device__ __forceinline__ float bf2f(short s) {
  unsigned u = ((unsigned)(unsigned short)s) << 16;
  return __builtin_bit_cast(float, u);
}
static __device__ __forceinline__ void gload16(const void* g, void* l) {
  __builtin_amdgcn_global_load_lds(
      (const __attribute__((address_space(1))) unsigned int*)g,
      (__attribute__((address_space(3))) unsigned int*)l, 16, 0, 0);
}
// lgkm-only barrier: does NOT drain in-flight global_load_lds (vmcnt)
static __device__ __forceinline__ void bar_lds() {
  __builtin_amdgcn_sched_barrier(0);
  asm volatile("s_waitcnt lgkmcnt(0)" ::: "memory");
  __builtin_amdgcn_s_barrier();
  __builtin_amdgcn_sched_barrier(0);
}

// w1t [128n][384k] bf16, w2t [128n][128k] bf16, nbf = bf16(nfeat), + passthrough
__global__ void convert_kernel(const float* __restrict__ W1,
                               const float* __restrict__ W2,
                               const float* __restrict__ nfeat,
                               short* __restrict__ w1t, short* __restrict__ w2t,
                               short* __restrict__ nbf, float* __restrict__ outn) {
  const int step = gridDim.x * blockDim.x;
  const int t0 = blockIdx.x * blockDim.x + threadIdx.x;
  for (int i = t0; i < 384 * 128; i += step) {
    int n = i / 384, k = i - n * 384;
    w1t[i] = f2bf(W1[k * 128 + n]);
  }
  for (int i = t0; i < 128 * 128; i += step) {
    int n = i >> 7, k = i & 127;
    w2t[i] = f2bf(W2[k * 128 + n]);
  }
  for (int i = t0; i < N_NODES * 128 / 4; i += step) {
    f32x4 v = *(const f32x4*)(nfeat + (size_t)i * 4);
    short o4[4];
#pragma unroll
    for (int q = 0; q < 4; ++q) o4[q] = f2bf(v[q]);
    *(unsigned long long*)(nbf + (size_t)i * 4) = *(unsigned long long*)o4;
    *(f32x4*)(outn + (size_t)i * 4) = v;  // passthrough output 1
  }
}

// Persistent: 512 blocks x 256 threads (4 waves), 2 blocks/CU. Tile = 64 edges.
// Wave w owns output cols [32w,32w+32) (2 n-frags). Weights register-resident
// (launch_bounds(256,2): 256-VGPR cap). 3 barriers/tile. LN fused into flush.
__global__ __launch_bounds__(256, 2) void edge_mlp_persistent(
    const float* __restrict__ efeat, const short* __restrict__ nbf,
    const int* __restrict__ src, const int* __restrict__ dst,
    const short* __restrict__ w1t, const short* __restrict__ w2t,
    const float* __restrict__ b1, const float* __restrict__ b2,
    const float* __restrict__ gamma, const float* __restrict__ beta,
    float* __restrict__ out) {
  __shared__ __align__(16) char smem[66560];
  char* catA = smem;                   // [64][256B] bf16 efeat-seg, swz; later x
  char* catB = smem + 16384;           // [64][512B] bf16 src|dst gathers, swz
  char* Hbuf = smem + 49152;           // [64][256B] bf16 H, swz
  float* gb = (float*)(smem + 65536);  // gamma[128], beta[128]

  const int tid = threadIdx.x;
  const int lane = tid & 63;
  const int w = tid >> 6;      // wave 0..3
  const int lrow = lane & 15;  // A row / C col
  const int kgrp = (lane >> 4) & 3;

  gb[tid] = (tid < 128) ? gamma[tid] : beta[tid - 128];  // once per block

  // ---- weights resident in registers ----
  bf16x8 B1[24], B2[8];
#pragma unroll
  for (int ks = 0; ks < 12; ++ks)
#pragma unroll
    for (int n = 0; n < 2; ++n)
      B1[ks * 2 + n] =
          *(const bf16x8*)(w1t + (w * 32 + n * 16 + lrow) * 384 + ks * 32 + kgrp * 8);
#pragma unroll
  for (int ks = 0; ks < 4; ++ks)
#pragma unroll
    for (int n = 0; n < 2; ++n)
      B2[ks * 2 + n] =
          *(const bf16x8*)(w2t + (w * 32 + n * 16 + lrow) * 128 + ks * 32 + kgrp * 8);
  float b1v[2], b2v[2];
#pragma unroll
  for (int n = 0; n < 2; ++n) {
    b1v[n] = b1[w * 32 + n * 16 + lrow];
    b2v[n] = b2[w * 32 + n * 16 + lrow];
  }

  // ---- gather statics: 8 global_load_lds per wave, pre-swizzled source ----
  int grow[8], gseg[8], gkb[8];
#pragma unroll
  for (int i = 0; i < 8; ++i) {
    int F = w * 8192 + i * 1024 + lane * 16;  // linear catB byte offset
    grow[i] = F >> 9;
    int win = (F & 511) ^ ((grow[i] & 15) << 4);  // involution, seg bit untouched
    gseg[i] = win >> 8;
    gkb[i] = win & 255;
  }

  // flush mapping: 4 threads/row, 32 consecutive cols each
  const int frow = tid >> 2;
  const int fc = (tid & 3) * 32;
  const int fswz = (frow & 15) << 4;

  f32x4 S[8];
  auto stage_S = [&](int t) {
    int e = t * 64 + frow;
    e = e < N_EDGES ? e : (N_EDGES - 1);
    const float* p = efeat + (size_t)e * 128 + fc;
#pragma unroll
    for (int q = 0; q < 8; ++q) S[q] = *(const f32x4*)(p + q * 4);
  };
  auto write_catA = [&]() {
#pragma unroll
    for (int c = 0; c < 4; ++c) {
      bf16x8 v;
#pragma unroll
      for (int j = 0; j < 4; ++j) {
        v[j] = f2bf(S[2 * c][j]);
        v[4 + j] = f2bf(S[2 * c + 1][j]);
      }
      *(bf16x8*)(catA + frow * 256 + ((fc * 2 + c * 16) ^ fswz)) = v;
    }
  };
  auto issue_gathers = [&](int t) {
#pragma unroll
    for (int i = 0; i < 8; ++i) {
      int e = t * 64 + grow[i];
      e = e < N_EDGES ? e : (N_EDGES - 1);
      int node = gseg[i] ? dst[e] : src[e];
      gload16((const char*)nbf + (size_t)node * 256 + gkb[i],
              catB + w * 8192 + i * 1024);
    }
  };

  // ---- prologue ----
  const int t0 = blockIdx.x;
  stage_S(t0);
  write_catA();
  issue_gathers(t0);

  for (int t = t0; t < NT; t += GRID) {
    __syncthreads();  // drains vmcnt: cat(t) ready

    // residual capture (bf16) before catA is reused for x
    bf16x8 rz[4];
#pragma unroll
    for (int c = 0; c < 4; ++c)
      rz[c] = *(const bf16x8*)(catA + frow * 256 + ((fc * 2 + c * 16) ^ fswz));

    // ---- GEMM1: K=384 ----
    f32x4 acc[4][2];
#pragma unroll
    for (int m = 0; m < 4; ++m)
#pragma unroll
      for (int n = 0; n < 2; ++n) acc[m][n] = (f32x4)0.f;
#pragma unroll
    for (int ks = 0; ks < 12; ++ks) {
      bf16x8 a[4];
#pragma unroll
      for (int m = 0; m < 4; ++m) {
        int row = m * 16 + lrow;
        int sw = (row & 15) << 4;
        a[m] = (ks < 4)
                   ? *(const bf16x8*)(catA + row * 256 + ((ks * 64 + kgrp * 16) ^ sw))
                   : *(const bf16x8*)(catB + row * 512 +
                                      (((ks - 4) * 64 + kgrp * 16) ^ sw));
      }
#pragma unroll
      for (int m = 0; m < 4; ++m)
#pragma unroll
        for (int n = 0; n < 2; ++n)
          acc[m][n] =
              __builtin_amdgcn_mfma_f32_16x16x32_bf16(a[m], B1[ks * 2 + n], acc[m][n], 0, 0, 0);
    }

    // ---- bias1 + SiLU -> Hbuf ----
#pragma unroll
    for (int m = 0; m < 4; ++m)
#pragma unroll
      for (int n = 0; n < 2; ++n)
#pragma unroll
        for (int r = 0; r < 4; ++r) {
          float x = acc[m][n][r] + b1v[n];
          float h = x / (1.f + __expf(-x));
          int row = m * 16 + kgrp * 4 + r;  // C/D: row=(lane>>4)*4+reg
          int col = w * 32 + n * 16 + lrow; // C/D: col=lane&15
          *(short*)(Hbuf + row * 256 + ((col * 2) ^ ((row & 15) << 4))) = f2bf(h);
        }
    bar_lds();  // H ready; cat(t) fully consumed

    // ---- prefetch next tile (stage loads FIRST, gathers second) ----
    const int tn = t + GRID;
    if (tn < NT) {
      stage_S(tn);
      issue_gathers(tn);
    }

    // ---- GEMM2: K=128 ----
    f32x4 acc2[4][2];
#pragma unroll
    for (int m = 0; m < 4; ++m)
#pragma unroll
      for (int n = 0; n < 2; ++n) acc2[m][n] = (f32x4)0.f;
#pragma unroll
    for (int ks = 0; ks < 4; ++ks) {
      bf16x8 a[4];
#pragma unroll
      for (int m = 0; m < 4; ++m) {
        int row = m * 16 + lrow;
        a[m] = *(const bf16x8*)(Hbuf + row * 256 +
                                ((ks * 64 + kgrp * 16) ^ ((row & 15) << 4)));
      }
#pragma unroll
      for (int m = 0; m < 4; ++m)
#pragma unroll
        for (int n = 0; n < 2; ++n)
          acc2[m][n] =
              __builtin_amdgcn_mfma_f32_16x16x32_bf16(a[m], B2[ks * 2 + n], acc2[m][n], 0, 0, 0);
    }

    // ---- x = acc2 + b2 -> catA (bf16, overwrites cat; GEMM1 reads done) ----
#pragma unroll
    for (int m = 0; m < 4; ++m)
#pragma unroll
      for (int n = 0; n < 2; ++n)
#pragma unroll
        for (int r = 0; r < 4; ++r) {
          float x = acc2[m][n][r] + b2v[n];
          int row = m * 16 + kgrp * 4 + r;
          int col = w * 32 + n * 16 + lrow;
          *(short*)(catA + row * 256 + ((col * 2) ^ ((row & 15) << 4))) = f2bf(x);
        }
    bar_lds();  // x ready

    // ---- fused LN stats + normalize + residual + store ----
    bf16x8 xv[4];
#pragma unroll
    for (int c = 0; c < 4; ++c)
      xv[c] = *(const bf16x8*)(catA + frow * 256 + ((fc * 2 + c * 16) ^ fswz));
    float s1 = 0.f, s2 = 0.f;
#pragma unroll
    for (int c = 0; c < 4; ++c)
#pragma unroll
      for (int j = 0; j < 8; ++j) {
        float f = bf2f(xv[c][j]);
        s1 += f;
        s2 += f * f;
      }
    s1 += __shfl_xor(s1, 1, 64); s2 += __shfl_xor(s2, 1, 64);
    s1 += __shfl_xor(s1, 2, 64); s2 += __shfl_xor(s2, 2, 64);
    float mu = s1 * (1.f / 128.f);
    float var = s2 * (1.f / 128.f) - mu * mu;
    float rs = rsqrtf(var + LN_EPS);

    int e = t * 64 + frow;
    if (e < N_EDGES) {
      float* op = out + (size_t)e * 128 + fc;
#pragma unroll
      for (int c = 0; c < 4; ++c) {
        f32x4 v0, v1;
#pragma unroll
        for (int j = 0; j < 4; ++j) {
          int cj = fc + c * 8 + j;
          v0[j] = (bf2f(xv[c][j]) - mu) * rs * gb[cj] + gb[128 + cj] + bf2f(rz[c][j]);
          v1[j] = (bf2f(xv[c][4 + j]) - mu) * rs * gb[cj + 4] + gb[128 + cj + 4] +
                  bf2f(rz[c][4 + j]);
        }
        *(f32x4*)(op + c * 8) = v0;
        *(f32x4*)(op + c * 8 + 4) = v1;
      }
    }
    // own chunk: same thread read rz/xv above -> safe to overwrite
    write_catA();
  }
}

// ---- fallback (tiny ws): block-per-edge, fp32 ----
__global__ void edge_simple(const float* __restrict__ efeat, const float* __restrict__ nfeat,
                            const int* __restrict__ src, const int* __restrict__ dst,
                            const float* __restrict__ W1, const float* __restrict__ b1,
                            const float* __restrict__ W2, const float* __restrict__ b2,
                            const float* __restrict__ g, const float* __restrict__ be,
                            float* __restrict__ out) {
  int e = blockIdx.x, j = threadIdx.x;
  __shared__ float cat[384], h[128], red[128];
  cat[j] = efeat[(size_t)e * 128 + j];
  cat[128 + j] = nfeat[(size_t)src[e] * 128 + j];
  cat[256 + j] = nfeat[(size_t)dst[e] * 128 + j];
  __syncthreads();
  float s = b1[j];
  for (int k = 0; k < 384; ++k) s += cat[k] * W1[k * 128 + j];
  h[j] = s / (1.f + expf(-s));
  __syncthreads();
  float o = b2[j];
  for (int k = 0; k < 128; ++k) o += h[k] * W2[k * 128 + j];
  red[j] = o;
  __syncthreads();
  __shared__ float mu, rs;
  if (j == 0) {
    float s1 = 0, s2 = 0;
    for (int k = 0; k < 128; ++k) { s1 += red[k]; s2 += red[k] * red[k]; }
    mu = s1 / 128.f;
    rs = rsqrtf(s2 / 128.f - mu * mu + LN_EPS);
  }
  __syncthreads();
  out[(size_t)e * 128 + j] = (o - mu) * rs * g[j] + be[j] + efeat[(size_t)e * 128 + j];
}

extern "C" void kernel_launch(void* const* d_in, const int* in_sizes, int n_in,
                              void* d_out, int out_size, void* d_ws, size_t ws_size,
                              hipStream_t stream) {
  const float* efeat = (const float*)d_in[0];
  const float* nfeat = (const float*)d_in[1];
  const int* src = (const int*)d_in[2];
  const int* dst = (const int*)d_in[3];
  const float* W1 = (const float*)d_in[4];
  const float* b1 = (const float*)d_in[5];
  const float* W2 = (const float*)d_in[6];
  const float* b2 = (const float*)d_in[7];
  const float* gamma = (const float*)d_in[8];
  const float* beta = (const float*)d_in[9];
  float* out = (float*)d_out;

  short* w1t = (short*)d_ws;         // 96 KB
  short* w2t = w1t + 384 * 128;      // 32 KB
  short* nbf = w2t + 128 * 128;      // 12.8 MB
  const size_t need =
      (size_t)(384 * 128 + 128 * 128 + (size_t)N_NODES * 128) * sizeof(short);

  if (ws_size >= need) {
    convert_kernel<<<1024, 256, 0, stream>>>(W1, W2, nfeat, w1t, w2t, nbf,
                                             out + (size_t)N_EDGES * 128);
    edge_mlp_persistent<<<GRID, 256, 0, stream>>>(efeat, nbf, src, dst, w1t, w2t,
                                                  b1, b2, gamma, beta, out);
  } else {
    hipMemcpyAsync(out + (size_t)N_EDGES * 128, nfeat,
                   (size_t)N_NODES * 128 * sizeof(float),
                   hipMemcpyDeviceToDevice, stream);
    edge_simple<<<N_EDGES, 128, 0, stream>>>(efeat, nfeat, src, dst, W1, b1, W2,
                                             b2, gamma, beta, out);
  }
}

// Round 10
// 490.725 us; speedup vs baseline: 1.0200x; 1.0200x over previous
//
#include <hip/hip_runtime.h>
#include <hip/hip_bf16.h>

#define N_EDGES 500000
#define N_NODES 50000
#define NT ((N_EDGES + 63) / 64)  // 7813 tiles of 64 edges
#define GRID 768
#define LN_EPS 1e-5f

typedef __attribute__((ext_vector_type(8))) short bf16x8;
typedef __attribute__((ext_vector_type(4))) short bf16x4;
typedef __attribute__((ext_vector_type(4))) float f32x4;

static __device__ __forceinline__ short f2bf(float f) {
  return __builtin_bit_cast(short, __float2bfloat16(f));
}
static __device__ __forceinline__ float bf2f(short s) {
  unsigned u = ((unsigned)(unsigned short)s) << 16;
  return __builtin_bit_cast(float, u);
}
static __device__ __forceinline__ void gload16(const void* g, void* l) {
  __builtin_amdgcn_global_load_lds(
      (const __attribute__((address_space(1))) unsigned int*)g,
      (__attribute__((address_space(3))) unsigned int*)l, 16, 0, 0);
}
// lgkm-only barrier: does NOT drain in-flight global_load_lds (vmcnt)
static __device__ __forceinline__ void bar_lds() {
  __builtin_amdgcn_sched_barrier(0);
  asm volatile("s_waitcnt lgkmcnt(0)" ::: "memory");
  __builtin_amdgcn_s_barrier();
  __builtin_amdgcn_sched_barrier(0);
}

// w1t [128n][384k] bf16, w2t [128n][128k] bf16, nbf = bf16(nfeat), + passthrough
__global__ void convert_kernel(const float* __restrict__ W1,
                               const float* __restrict__ W2,
                               const float* __restrict__ nfeat,
                               short* __restrict__ w1t, short* __restrict__ w2t,
                               short* __restrict__ nbf, float* __restrict__ outn) {
  const int step = gridDim.x * blockDim.x;
  const int t0 = blockIdx.x * blockDim.x + threadIdx.x;
  for (int i = t0; i < 384 * 128; i += step) {
    int n = i / 384, k = i - n * 384;
    w1t[i] = f2bf(W1[k * 128 + n]);
  }
  for (int i = t0; i < 128 * 128; i += step) {
    int n = i >> 7, k = i & 127;
    w2t[i] = f2bf(W2[k * 128 + n]);
  }
  for (int i = t0; i < N_NODES * 128 / 4; i += step) {
    f32x4 v = *(const f32x4*)(nfeat + (size_t)i * 4);
    short o4[4];
#pragma unroll
    for (int q = 0; q < 4; ++q) o4[q] = f2bf(v[q]);
    *(unsigned long long*)(nbf + (size_t)i * 4) = *(unsigned long long*)o4;
    *(f32x4*)(outn + (size_t)i * 4) = v;  // passthrough output 1
  }
}

// Persistent: 768 blocks x 512 threads (8 waves), LDS 48KB -> 3 blocks/CU
// = 24 waves/CU. Tile = 64 edges. Wave w owns output cols [16w,16w+16).
// catA overlaid: efeat-seg -> H -> x (residual captured to regs).
__global__ __launch_bounds__(512, 6) void edge_mlp_persistent(
    const float* __restrict__ efeat, const short* __restrict__ nbf,
    const int* __restrict__ src, const int* __restrict__ dst,
    const short* __restrict__ w1t, const short* __restrict__ w2t,
    const float* __restrict__ b1, const float* __restrict__ b2,
    const float* __restrict__ gamma, const float* __restrict__ beta,
    float* __restrict__ out) {
  __shared__ __align__(16) char smem[49152];
  char* catA = smem;          // [64][256B] bf16 swz: efeat-seg, then H, then x
  char* catB = smem + 16384;  // [64][512B] bf16 swz: src|dst gathers

  const int tid = threadIdx.x;
  const int lane = tid & 63;
  const int w = tid >> 6;      // wave 0..7
  const int lrow = lane & 15;  // A-frag row / C-frag col
  const int kgrp = (lane >> 4) & 3;
  const int col = w * 16 + lrow;  // this lane's output column
  const float b1v = b1[col], b2v = b2[col];

  // flush/stage mapping: 64 rows x 32 f32x4-chunks; per-instruction lanes
  // 0-31 cover one full 512B row -> 1KB contiguous per wave-instruction.
  const int frow0 = tid >> 5;  // 0..15 (rows frow0 + 16*it)
  const int fc4 = tid & 31;    // float4-chunk within row
  const f32x4 gv = *(const f32x4*)(gamma + fc4 * 4);
  const f32x4 bev = *(const f32x4*)(beta + fc4 * 4);

  f32x4 S[4];  // staged efeat fp32 for next tile
  auto stage_S = [&](int t) {
#pragma unroll
    for (int it = 0; it < 4; ++it) {
      int e = t * 64 + frow0 + it * 16;
      e = e < N_EDGES ? e : (N_EDGES - 1);
      S[it] = *(const f32x4*)(efeat + (size_t)e * 128 + fc4 * 4);
    }
  };
  auto write_catA = [&]() {
#pragma unroll
    for (int it = 0; it < 4; ++it) {
      int row = frow0 + it * 16;
      bf16x4 v;
#pragma unroll
      for (int j = 0; j < 4; ++j) v[j] = f2bf(S[it][j]);
      *(bf16x4*)(catA + row * 256 + ((fc4 * 8) ^ ((row & 15) << 4))) = v;
    }
  };
  auto issue_gathers = [&](int t) {
#pragma unroll
    for (int i = 0; i < 4; ++i) {
      int F = w * 4096 + i * 1024 + lane * 16;     // linear catB byte offset
      int grow = F >> 9;                           // row 0..63
      int win = (F & 511) ^ ((grow & 15) << 4);    // pre-swizzle (involution)
      int e = t * 64 + grow;
      e = e < N_EDGES ? e : (N_EDGES - 1);
      int node = (win >> 8) ? dst[e] : src[e];
      gload16((const char*)nbf + (size_t)node * 256 + (win & 255),
              catB + w * 4096 + i * 1024);
    }
  };

  // ---- prologue ----
  const int t0 = blockIdx.x;
  stage_S(t0);
  write_catA();
  issue_gathers(t0);

  for (int t = t0; t < NT; t += GRID) {
    __syncthreads();  // drains vmcnt+lgkm: catA/catB(t) ready

    // residual capture (bf16) before catA is overlaid by H
    bf16x4 rz[4];
#pragma unroll
    for (int it = 0; it < 4; ++it) {
      int row = frow0 + it * 16;
      rz[it] = *(const bf16x4*)(catA + row * 256 + ((fc4 * 8) ^ ((row & 15) << 4)));
    }

    // ---- GEMM1: K=384 (catA k<128, catB k>=128) ----
    f32x4 acc[4];
#pragma unroll
    for (int m = 0; m < 4; ++m) acc[m] = (f32x4)0.f;
#pragma unroll
    for (int ks = 0; ks < 12; ++ks) {
      bf16x8 b = *(const bf16x8*)(w1t + col * 384 + ks * 32 + kgrp * 8);
      bf16x8 a[4];
#pragma unroll
      for (int m = 0; m < 4; ++m) {
        int row = m * 16 + lrow;
        int sw = (row & 15) << 4;
        a[m] = (ks < 4)
                   ? *(const bf16x8*)(catA + row * 256 + ((ks * 64 + kgrp * 16) ^ sw))
                   : *(const bf16x8*)(catB + row * 512 +
                                      (((ks - 4) * 64 + kgrp * 16) ^ sw));
      }
#pragma unroll
      for (int m = 0; m < 4; ++m)
        acc[m] = __builtin_amdgcn_mfma_f32_16x16x32_bf16(a[m], b, acc[m], 0, 0, 0);
    }
    __syncthreads();  // all cat reads done (no async loads in flight here)

    // ---- prefetch next tile: gathers (catB now free) + efeat to regs ----
    const int tn = t + GRID;
    if (tn < NT) {
      issue_gathers(tn);
      stage_S(tn);
    }

    // ---- bias1 + SiLU -> H overlays catA ----
#pragma unroll
    for (int m = 0; m < 4; ++m)
#pragma unroll
      for (int r = 0; r < 4; ++r) {
        float x = acc[m][r] + b1v;
        float h = x / (1.f + __expf(-x));
        int row = m * 16 + kgrp * 4 + r;  // C/D: row=(lane>>4)*4+reg
        *(short*)(catA + row * 256 + ((col * 2) ^ ((row & 15) << 4))) = f2bf(h);
      }
    bar_lds();  // H visible (gathers for tn stay in flight)

    // ---- GEMM2: K=128 from H ----
    f32x4 acc2[4];
#pragma unroll
    for (int m = 0; m < 4; ++m) acc2[m] = (f32x4)0.f;
#pragma unroll
    for (int ks = 0; ks < 4; ++ks) {
      bf16x8 b = *(const bf16x8*)(w2t + col * 128 + ks * 32 + kgrp * 8);
      bf16x8 a[4];
#pragma unroll
      for (int m = 0; m < 4; ++m) {
        int row = m * 16 + lrow;
        a[m] = *(const bf16x8*)(catA + row * 256 +
                                ((ks * 64 + kgrp * 16) ^ ((row & 15) << 4)));
      }
#pragma unroll
      for (int m = 0; m < 4; ++m)
        acc2[m] = __builtin_amdgcn_mfma_f32_16x16x32_bf16(a[m], b, acc2[m], 0, 0, 0);
    }
    bar_lds();  // all H reads complete

    // ---- x = acc2 + b2 overlays catA (H dead) ----
#pragma unroll
    for (int m = 0; m < 4; ++m)
#pragma unroll
      for (int r = 0; r < 4; ++r) {
        float x = acc2[m][r] + b2v;
        int row = m * 16 + kgrp * 4 + r;
        *(short*)(catA + row * 256 + ((col * 2) ^ ((row & 15) << 4))) = f2bf(x);
      }
    bar_lds();  // x visible

    // ---- fused LN + residual + coalesced store ----
#pragma unroll
    for (int it = 0; it < 4; ++it) {
      int row = frow0 + it * 16;
      bf16x4 xv = *(const bf16x4*)(catA + row * 256 + ((fc4 * 8) ^ ((row & 15) << 4)));
      float xf[4];
      float s1 = 0.f, s2 = 0.f;
#pragma unroll
      for (int j = 0; j < 4; ++j) {
        xf[j] = bf2f(xv[j]);
        s1 += xf[j];
        s2 += xf[j] * xf[j];
      }
#pragma unroll
      for (int off = 1; off < 32; off <<= 1) {
        s1 += __shfl_xor(s1, off, 64);
        s2 += __shfl_xor(s2, off, 64);
      }
      float mu = s1 * (1.f / 128.f);
      float var = s2 * (1.f / 128.f) - mu * mu;
      float rs = rsqrtf(var + LN_EPS);
      int e = t * 64 + row;
      if (e < N_EDGES) {
        f32x4 o;
#pragma unroll
        for (int j = 0; j < 4; ++j)
          o[j] = (xf[j] - mu) * rs * gv[j] + bev[j] + bf2f(rz[it][j]);
        *(f32x4*)(out + (size_t)e * 128 + fc4 * 4) = o;
      }
    }
    // own chunks only (same thread read x/rz above): no barrier needed
    if (tn < NT) write_catA();
  }
}

// ---- fallback (tiny ws): block-per-edge, fp32 ----
__global__ void edge_simple(const float* __restrict__ efeat, const float* __restrict__ nfeat,
                            const int* __restrict__ src, const int* __restrict__ dst,
                            const float* __restrict__ W1, const float* __restrict__ b1,
                            const float* __restrict__ W2, const float* __restrict__ b2,
                            const float* __restrict__ g, const float* __restrict__ be,
                            float* __restrict__ out) {
  int e = blockIdx.x, j = threadIdx.x;
  __shared__ float cat[384], h[128], red[128];
  cat[j] = efeat[(size_t)e * 128 + j];
  cat[128 + j] = nfeat[(size_t)src[e] * 128 + j];
  cat[256 + j] = nfeat[(size_t)dst[e] * 128 + j];
  __syncthreads();
  float s = b1[j];
  for (int k = 0; k < 384; ++k) s += cat[k] * W1[k * 128 + j];
  h[j] = s / (1.f + expf(-s));
  __syncthreads();
  float o = b2[j];
  for (int k = 0; k < 128; ++k) o += h[k] * W2[k * 128 + j];
  red[j] = o;
  __syncthreads();
  __shared__ float mu, rs;
  if (j == 0) {
    float s1 = 0, s2 = 0;
    for (int k = 0; k < 128; ++k) { s1 += red[k]; s2 += red[k] * red[k]; }
    mu = s1 / 128.f;
    rs = rsqrtf(s2 / 128.f - mu * mu + LN_EPS);
  }
  __syncthreads();
  out[(size_t)e * 128 + j] = (o - mu) * rs * g[j] + be[j] + efeat[(size_t)e * 128 + j];
}

extern "C" void kernel_launch(void* const* d_in, const int* in_sizes, int n_in,
                              void* d_out, int out_size, void* d_ws, size_t ws_size,
                              hipStream_t stream) {
  const float* efeat = (const float*)d_in[0];
  const float* nfeat = (const float*)d_in[1];
  const int* src = (const int*)d_in[2];
  const int* dst = (const int*)d_in[3];
  const float* W1 = (const float*)d_in[4];
  const float* b1 = (const float*)d_in[5];
  const float* W2 = (const float*)d_in[6];
  const float* b2 = (const float*)d_in[7];
  const float* gamma = (const float*)d_in[8];
  const float* beta = (const float*)d_in[9];
  float* out = (float*)d_out;

  short* w1t = (short*)d_ws;         // 96 KB
  short* w2t = w1t + 384 * 128;      // 32 KB
  short* nbf = w2t + 128 * 128;      // 12.8 MB
  const size_t need =
      (size_t)(384 * 128 + 128 * 128 + (size_t)N_NODES * 128) * sizeof(short);

  if (ws_size >= need) {
    convert_kernel<<<1024, 256, 0, stream>>>(W1, W2, nfeat, w1t, w2t, nbf,
                                             out + (size_t)N_EDGES * 128);
    edge_mlp_persistent<<<GRID, 512, 0, stream>>>(efeat, nbf, src, dst, w1t, w2t,
                                                  b1, b2, gamma, beta, out);
  } else {
    hipMemcpyAsync(out + (size_t)N_EDGES * 128, nfeat,
                   (size_t)N_NODES * 128 * sizeof(float),
                   hipMemcpyDeviceToDevice, stream);
    edge_simple<<<N_EDGES, 128, 0, stream>>>(efeat, nfeat, src, dst, W1, b1, W2,
                                             b2, gamma, beta, out);
  }
}

// Round 11
// 340.288 us; speedup vs baseline: 1.4709x; 1.4421x over previous
//
#include <hip/hip_runtime.h>
#include <hip/hip_bf16.h>

#define N_EDGES 500000
#define N_NODES 50000
#define NT ((N_EDGES + 63) / 64)  // 7813 tiles of 64 edges
#define GRID 256
#define LN_EPS 1e-5f

typedef __attribute__((ext_vector_type(8))) short bf16x8;
typedef __attribute__((ext_vector_type(4))) short bf16x4;
typedef __attribute__((ext_vector_type(4))) float f32x4;

static __device__ __forceinline__ short f2bf(float f) {
  return __builtin_bit_cast(short, __float2bfloat16(f));
}
static __device__ __forceinline__ float bf2f(short s) {
  unsigned u = ((unsigned)(unsigned short)s) << 16;
  return __builtin_bit_cast(float, u);
}
static __device__ __forceinline__ void gload16(const void* g, void* l) {
  __builtin_amdgcn_global_load_lds(
      (const __attribute__((address_space(1))) unsigned int*)g,
      (__attribute__((address_space(3))) unsigned int*)l, 16, 0, 0);
}
// lgkm-only barrier: does NOT drain in-flight global_load_lds
static __device__ __forceinline__ void bar_lds() {
  __builtin_amdgcn_sched_barrier(0);
  asm volatile("s_waitcnt lgkmcnt(0)" ::: "memory");
  __builtin_amdgcn_s_barrier();
  __builtin_amdgcn_sched_barrier(0);
}
// counted barrier: keep the 4 just-issued gathers in flight, drain older
static __device__ __forceinline__ void bar_vm4() {
  __builtin_amdgcn_sched_barrier(0);
  asm volatile("s_waitcnt vmcnt(4) lgkmcnt(0)" ::: "memory");
  __builtin_amdgcn_s_barrier();
  __builtin_amdgcn_sched_barrier(0);
}

// w1t [128n][384k] bf16, w2t [128n][128k] bf16, nbf = bf16(nfeat), + passthrough
__global__ void convert_kernel(const float* __restrict__ W1,
                               const float* __restrict__ W2,
                               const float* __restrict__ nfeat,
                               short* __restrict__ w1t, short* __restrict__ w2t,
                               short* __restrict__ nbf, float* __restrict__ outn) {
  const int step = gridDim.x * blockDim.x;
  const int t0 = blockIdx.x * blockDim.x + threadIdx.x;
  for (int i = t0; i < 384 * 128; i += step) {
    int n = i / 384, k = i - n * 384;
    w1t[i] = f2bf(W1[k * 128 + n]);
  }
  for (int i = t0; i < 128 * 128; i += step) {
    int n = i >> 7, k = i & 127;
    w2t[i] = f2bf(W2[k * 128 + n]);
  }
  for (int i = t0; i < N_NODES * 128 / 4; i += step) {
    f32x4 v = *(const f32x4*)(nfeat + (size_t)i * 4);
    short o4[4];
#pragma unroll
    for (int q = 0; q < 4; ++q) o4[q] = f2bf(v[q]);
    *(unsigned long long*)(nbf + (size_t)i * 4) = *(unsigned long long*)o4;
    *(f32x4*)(outn + (size_t)i * 4) = v;  // passthrough output 1
  }
}

// Persistent pipelined: 256 blocks (1/CU) x 512 thr (8 waves). Tile = 64 edges.
// cat double-buffered; gathers for t+1 in flight across tile t (vmcnt(4)).
// 3 barriers/tile, no full vmcnt drain in the loop.
__global__ __launch_bounds__(512, 2) void edge_mlp_pipelined(
    const float* __restrict__ efeat, const short* __restrict__ nbf,
    const int* __restrict__ src, const int* __restrict__ dst,
    const short* __restrict__ w1t, const short* __restrict__ w2t,
    const float* __restrict__ b1, const float* __restrict__ b2,
    const float* __restrict__ gamma, const float* __restrict__ beta,
    float* __restrict__ out) {
  // buf0 [0,49152): ef [64][256B] + gathers [64][512B] @ +16384 ; buf1 next
  // H @ 98304 [64][256B]; xbuf @ 114688 [64][256B]; scr @ 131072 [64][16]f32;
  // gb @ 135168 [256]f32
  __shared__ __align__(16) char smem[136192];
  char* Hb = smem + 98304;
  char* xb = smem + 114688;
  float* scr = (float*)(smem + 131072);
  float* gb = (float*)(smem + 135168);

  const int tid = threadIdx.x;
  const int lane = tid & 63;
  const int w = tid >> 6;
  const int lrow = lane & 15;
  const int kgrp = (lane >> 4) & 3;
  const int col = w * 16 + lrow;
  const float b1v = b1[col], b2v = b2[col];
  if (tid < 256) gb[tid] = tid < 128 ? gamma[tid] : beta[tid - 128];

  // gather statics: 4 gload16/wave/tile; pre-swizzled source (involution)
  int grow[4], goff[4], gseg[4];
#pragma unroll
  for (int i = 0; i < 4; ++i) {
    int F = w * 4096 + i * 1024 + lane * 16;  // linear byte in gather region
    grow[i] = F >> 9;
    int win = F & 511;
    gseg[i] = win >> 8;
    goff[i] = (win & 255) ^ ((grow[i] & 15) << 4);
  }
  // stage/flush mapping: 8 threads/row, 16-B chunks
  const int frow = tid >> 3;
  const int fcb = tid & 7;
  const int fswz = (frow & 15) << 4;

  f32x4 S[4];
  auto stage_S = [&](int t) {
    int e = t * 64 + frow;
    e = e < N_EDGES ? e : (N_EDGES - 1);
#pragma unroll
    for (int it = 0; it < 4; ++it)
      S[it] = *(const f32x4*)(efeat + (size_t)e * 128 + (fcb + it * 8) * 4);
  };
  auto write_ef = [&](char* buf) {
#pragma unroll
    for (int it = 0; it < 4; ++it) {
      bf16x4 v;
#pragma unroll
      for (int j = 0; j < 4; ++j) v[j] = f2bf(S[it][j]);
      *(bf16x4*)(buf + frow * 256 + (((fcb + it * 8) * 8) ^ fswz)) = v;
    }
  };
  int idxN[4];
  auto load_idx = [&](int t, int* ix) {
#pragma unroll
    for (int i = 0; i < 4; ++i) {
      int e = t * 64 + grow[i];
      e = e < N_EDGES ? e : (N_EDGES - 1);
      ix[i] = gseg[i] ? dst[e] : src[e];
    }
  };
  auto issue_g = [&](char* buf, const int* ix) {
#pragma unroll
    for (int i = 0; i < 4; ++i)
      gload16((const char*)nbf + (size_t)ix[i] * 256 + goff[i],
              buf + 16384 + w * 4096 + i * 1024);
  };

  // ---- prologue ----
  const int t0 = blockIdx.x;
  char* cur = smem;
  char* nxt = smem + 49152;
  {
    int ix0[4];
    load_idx(t0, ix0);       // auto-waited at use
    stage_S(t0);
    write_ef(cur);
    issue_g(cur, ix0);       // gathers(t0) -> cur
    load_idx(t0 + GRID, idxN);
  }

  for (int t = t0; t < NT; t += GRID) {
    // top: prefetch tile t+1 (cat[nxt] free since D(t-1))
    stage_S(t + GRID);       // ef(t+1) -> S regs
    issue_g(nxt, idxN);      // gathers(t+1) -> nxt (uses idx; FIFO drains older)
    bar_vm4();               // A: cur ready (own gathers(t) drained; peers via barrier)
    load_idx(t + 2 * GRID, idxN);  // indices for t+2 (consumed next top)

    // ---- GEMM1: K=384 from cur ----
    bf16x8 B1[12];
#pragma unroll
    for (int ks = 0; ks < 12; ++ks)
      B1[ks] = *(const bf16x8*)(w1t + col * 384 + ks * 32 + kgrp * 8);
    f32x4 acc[4];
#pragma unroll
    for (int m = 0; m < 4; ++m) acc[m] = (f32x4)0.f;
#pragma unroll
    for (int ks = 0; ks < 12; ++ks) {
      bf16x8 a[4];
#pragma unroll
      for (int m = 0; m < 4; ++m) {
        int row = m * 16 + lrow;
        int sw = (row & 15) << 4;
        a[m] = (ks < 4)
                   ? *(const bf16x8*)(cur + row * 256 + ((ks * 64 + kgrp * 16) ^ sw))
                   : *(const bf16x8*)(cur + 16384 + row * 512 +
                                      (((ks - 4) * 64 + kgrp * 16) ^ sw));
      }
#pragma unroll
      for (int m = 0; m < 4; ++m)
        acc[m] = __builtin_amdgcn_mfma_f32_16x16x32_bf16(a[m], B1[ks], acc[m], 0, 0, 0);
    }

    // ---- bias1 + SiLU -> H ----
#pragma unroll
    for (int m = 0; m < 4; ++m)
#pragma unroll
      for (int r = 0; r < 4; ++r) {
        float x = acc[m][r] + b1v;
        float h = x / (1.f + __expf(-x));
        int row = m * 16 + kgrp * 4 + r;
        *(short*)(Hb + row * 256 + ((col * 2) ^ ((row & 15) << 4))) = f2bf(h);
      }
    bar_lds();  // C: H visible

    // ---- GEMM2: K=128 from H ----
    bf16x8 B2[4];
#pragma unroll
    for (int ks = 0; ks < 4; ++ks)
      B2[ks] = *(const bf16x8*)(w2t + col * 128 + ks * 32 + kgrp * 8);
    f32x4 acc2[4];
#pragma unroll
    for (int m = 0; m < 4; ++m) acc2[m] = (f32x4)0.f;
#pragma unroll
    for (int ks = 0; ks < 4; ++ks) {
      bf16x8 a[4];
#pragma unroll
      for (int m = 0; m < 4; ++m) {
        int row = m * 16 + lrow;
        a[m] = *(const bf16x8*)(Hb + row * 256 +
                                ((ks * 64 + kgrp * 16) ^ ((row & 15) << 4)));
      }
#pragma unroll
      for (int m = 0; m < 4; ++m)
        acc2[m] = __builtin_amdgcn_mfma_f32_16x16x32_bf16(a[m], B2[ks], acc2[m], 0, 0, 0);
    }

    // ---- x -> xbuf (bf16) + per-wave LN partials -> scr ----
#pragma unroll
    for (int m = 0; m < 4; ++m)
#pragma unroll
      for (int r = 0; r < 4; ++r) {
        float x = acc2[m][r] + b2v;
        float s1 = x, s2 = x * x;
#pragma unroll
        for (int off = 1; off < 16; off <<= 1) {
          s1 += __shfl_xor(s1, off, 64);
          s2 += __shfl_xor(s2, off, 64);
        }
        int row = m * 16 + kgrp * 4 + r;
        if (lrow == 0) {
          scr[row * 16 + w * 2] = s1;
          scr[row * 16 + w * 2 + 1] = s2;
        }
        *(short*)(xb + row * 256 + ((col * 2) ^ ((row & 15) << 4))) = f2bf(x);
      }
    bar_lds();  // D: x + partials visible (also: all H reads complete)

    // ---- fused LN + residual + coalesced store ----
    {
      float s1 = 0.f, s2 = 0.f;
#pragma unroll
      for (int q = 0; q < 8; ++q) {
        s1 += scr[frow * 16 + q * 2];
        s2 += scr[frow * 16 + q * 2 + 1];
      }
      float mu = s1 * (1.f / 128.f);
      float var = s2 * (1.f / 128.f) - mu * mu;
      float rs = rsqrtf(var + LN_EPS);
      int e = t * 64 + frow;
      if (e < N_EDGES) {
        float* op = out + (size_t)e * 128;
#pragma unroll
        for (int it = 0; it < 4; ++it) {
          int c4 = fcb + it * 8;
          bf16x4 xv = *(const bf16x4*)(xb + frow * 256 + ((c4 * 8) ^ fswz));
          bf16x4 rv = *(const bf16x4*)(cur + frow * 256 + ((c4 * 8) ^ fswz));
          f32x4 g = *(const f32x4*)(gb + c4 * 4);
          f32x4 be = *(const f32x4*)(gb + 128 + c4 * 4);
          f32x4 o;
#pragma unroll
          for (int j = 0; j < 4; ++j)
            o[j] = (bf2f(xv[j]) - mu) * rs * g[j] + be[j] + bf2f(rv[j]);
          *(f32x4*)(op + c4 * 4) = o;
        }
      }
    }
    write_ef(nxt);  // ef(t+1); visible to all at A(t+1) via lgkmcnt
    char* tmp = cur; cur = nxt; nxt = tmp;
  }
  asm volatile("s_waitcnt vmcnt(0)" ::: "memory");  // drain before endpgm
}

// ---- fallback (tiny ws): block-per-edge, fp32 ----
__global__ void edge_simple(const float* __restrict__ efeat, const float* __restrict__ nfeat,
                            const int* __restrict__ src, const int* __restrict__ dst,
                            const float* __restrict__ W1, const float* __restrict__ b1,
                            const float* __restrict__ W2, const float* __restrict__ b2,
                            const float* __restrict__ g, const float* __restrict__ be,
                            float* __restrict__ out) {
  int e = blockIdx.x, j = threadIdx.x;
  __shared__ float cat[384], h[128], red[128];
  cat[j] = efeat[(size_t)e * 128 + j];
  cat[128 + j] = nfeat[(size_t)src[e] * 128 + j];
  cat[256 + j] = nfeat[(size_t)dst[e] * 128 + j];
  __syncthreads();
  float s = b1[j];
  for (int k = 0; k < 384; ++k) s += cat[k] * W1[k * 128 + j];
  h[j] = s / (1.f + expf(-s));
  __syncthreads();
  float o = b2[j];
  for (int k = 0; k < 128; ++k) o += h[k] * W2[k * 128 + j];
  red[j] = o;
  __syncthreads();
  __shared__ float mu, rs;
  if (j == 0) {
    float s1 = 0, s2 = 0;
    for (int k = 0; k < 128; ++k) { s1 += red[k]; s2 += red[k] * red[k]; }
    mu = s1 / 128.f;
    rs = rsqrtf(s2 / 128.f - mu * mu + LN_EPS);
  }
  __syncthreads();
  out[(size_t)e * 128 + j] = (o - mu) * rs * g[j] + be[j] + efeat[(size_t)e * 128 + j];
}

extern "C" void kernel_launch(void* const* d_in, const int* in_sizes, int n_in,
                              void* d_out, int out_size, void* d_ws, size_t ws_size,
                              hipStream_t stream) {
  const float* efeat = (const float*)d_in[0];
  const float* nfeat = (const float*)d_in[1];
  const int* src = (const int*)d_in[2];
  const int* dst = (const int*)d_in[3];
  const float* W1 = (const float*)d_in[4];
  const float* b1 = (const float*)d_in[5];
  const float* W2 = (const float*)d_in[6];
  const float* b2 = (const float*)d_in[7];
  const float* gamma = (const float*)d_in[8];
  const float* beta = (const float*)d_in[9];
  float* out = (float*)d_out;

  short* w1t = (short*)d_ws;         // 96 KB
  short* w2t = w1t + 384 * 128;      // 32 KB
  short* nbf = w2t + 128 * 128;      // 12.8 MB
  const size_t need =
      (size_t)(384 * 128 + 128 * 128 + (size_t)N_NODES * 128) * sizeof(short);

  if (ws_size >= need) {
    convert_kernel<<<1024, 256, 0, stream>>>(W1, W2, nfeat, w1t, w2t, nbf,
                                             out + (size_t)N_EDGES * 128);
    edge_mlp_pipelined<<<GRID, 512, 0, stream>>>(efeat, nbf, src, dst, w1t, w2t,
                                                 b1, b2, gamma, beta, out);
  } else {
    hipMemcpyAsync(out + (size_t)N_EDGES * 128, nfeat,
                   (size_t)N_NODES * 128 * sizeof(float),
                   hipMemcpyDeviceToDevice, stream);
    edge_simple<<<N_EDGES, 128, 0, stream>>>(efeat, nfeat, src, dst, W1, b1, W2,
                                             b2, gamma, beta, out);
  }
}

// Round 12
// 333.410 us; speedup vs baseline: 1.5013x; 1.0206x over previous
//
#include <hip/hip_runtime.h>
#include <hip/hip_bf16.h>

#define N_EDGES 500000
#define N_NODES 50000
#define NT ((N_EDGES + 63) / 64)  // 7813 tiles of 64 edges
#define GRID 256
#define LN_EPS 1e-5f

typedef __attribute__((ext_vector_type(8))) short bf16x8;
typedef __attribute__((ext_vector_type(4))) short bf16x4;
typedef __attribute__((ext_vector_type(4))) float f32x4;

static __device__ __forceinline__ short f2bf(float f) {
  return __builtin_bit_cast(short, __float2bfloat16(f));
}
static __device__ __forceinline__ float bf2f(short s) {
  unsigned u = ((unsigned)(unsigned short)s) << 16;
  return __builtin_bit_cast(float, u);
}
static __device__ __forceinline__ void gload16(const void* g, void* l) {
  __builtin_amdgcn_global_load_lds(
      (const __attribute__((address_space(1))) unsigned int*)g,
      (__attribute__((address_space(3))) unsigned int*)l, 16, 0, 0);
}
// lgkm-only barrier: does NOT drain in-flight global_load_lds
static __device__ __forceinline__ void bar_lds() {
  __builtin_amdgcn_sched_barrier(0);
  asm volatile("s_waitcnt lgkmcnt(0)" ::: "memory");
  __builtin_amdgcn_s_barrier();
  __builtin_amdgcn_sched_barrier(0);
}
// counted barrier: FIFO at this point = [gathers(t)4, stores(t-1)4, stageS4,
// gathers(t+1)4] -> vmcnt(8) drains gathers(t)+stores, keeps fresh 8 in flight
static __device__ __forceinline__ void bar_vm8() {
  __builtin_amdgcn_sched_barrier(0);
  asm volatile("s_waitcnt vmcnt(8) lgkmcnt(0)" ::: "memory");
  __builtin_amdgcn_s_barrier();
  __builtin_amdgcn_sched_barrier(0);
}

// w1t [128n][384k] bf16, w2t [128n][128k] bf16, nbf = bf16(nfeat), + passthrough
__global__ void convert_kernel(const float* __restrict__ W1,
                               const float* __restrict__ W2,
                               const float* __restrict__ nfeat,
                               short* __restrict__ w1t, short* __restrict__ w2t,
                               short* __restrict__ nbf, float* __restrict__ outn) {
  const int step = gridDim.x * blockDim.x;
  const int t0 = blockIdx.x * blockDim.x + threadIdx.x;
  for (int i = t0; i < 384 * 128; i += step) {
    int n = i / 384, k = i - n * 384;
    w1t[i] = f2bf(W1[k * 128 + n]);
  }
  for (int i = t0; i < 128 * 128; i += step) {
    int n = i >> 7, k = i & 127;
    w2t[i] = f2bf(W2[k * 128 + n]);
  }
  for (int i = t0; i < N_NODES * 128 / 4; i += step) {
    f32x4 v = *(const f32x4*)(nfeat + (size_t)i * 4);
    short o4[4];
#pragma unroll
    for (int q = 0; q < 4; ++q) o4[q] = f2bf(v[q]);
    *(unsigned long long*)(nbf + (size_t)i * 4) = *(unsigned long long*)o4;
    *(f32x4*)(outn + (size_t)i * 4) = v;  // passthrough output 1
  }
}

// Persistent pipelined: 256 blocks (1/CU) x 512 thr (8 waves). Tile = 64 edges.
// Wave (wm,wn)=(w>>2,w&3): rows [wm*32,+32) x cols [wn*32,+32). Weights
// loop-invariant in regs. cat double-buffered; 3 barriers/tile; no vmcnt(0).
__global__ __launch_bounds__(512, 2) void edge_mlp_pipelined(
    const float* __restrict__ efeat, const short* __restrict__ nbf,
    const int* __restrict__ src, const int* __restrict__ dst,
    const short* __restrict__ w1t, const short* __restrict__ w2t,
    const float* __restrict__ b1, const float* __restrict__ b2,
    const float* __restrict__ gamma, const float* __restrict__ beta,
    float* __restrict__ out) {
  // buf0 [0,49152): ef [64][256B] + gathers [64][512B] @ +16384 ; buf1 @49152
  // Hb @98304 [64][256B]; xb @114688 [64][256B]; gb @131072 [256]f32
  __shared__ __align__(16) char smem[132096];
  char* Hb = smem + 98304;
  char* xb = smem + 114688;
  float* gb = (float*)(smem + 131072);

  const int tid = threadIdx.x;
  const int lane = tid & 63;
  const int w = tid >> 6;
  const int wm = w >> 2;       // row-half 0/1
  const int wn = w & 3;        // col-quarter 0..3
  const int lrow = lane & 15;
  const int kgrp = (lane >> 4) & 3;
  if (tid < 256) gb[tid] = tid < 128 ? gamma[tid] : beta[tid - 128];

  // ---- loop-invariant weights & biases in registers ----
  bf16x8 B1[12][2], B2[4][2];
  float b1v[2], b2v[2];
#pragma unroll
  for (int n = 0; n < 2; ++n) {
    const int c = wn * 32 + n * 16 + lrow;
    b1v[n] = b1[c];
    b2v[n] = b2[c];
#pragma unroll
    for (int ks = 0; ks < 12; ++ks)
      B1[ks][n] = *(const bf16x8*)(w1t + c * 384 + ks * 32 + kgrp * 8);
#pragma unroll
    for (int ks = 0; ks < 4; ++ks)
      B2[ks][n] = *(const bf16x8*)(w2t + c * 128 + ks * 32 + kgrp * 8);
  }

  // gather statics: 4 gload16/wave/tile; pre-swizzled source (involution)
  int grow[4], goff[4], gseg[4];
#pragma unroll
  for (int i = 0; i < 4; ++i) {
    int F = w * 4096 + i * 1024 + lane * 16;
    grow[i] = F >> 9;
    int win = F & 511;
    gseg[i] = win >> 8;
    goff[i] = (win & 255) ^ ((grow[i] & 15) << 4);
  }
  // stage/flush mapping: 8 threads/row, 16-B chunks
  const int frow = tid >> 3;
  const int fcb = tid & 7;
  const int fswz = (frow & 15) << 4;

  f32x4 S[4];
  auto stage_S = [&](int t) {
    int e = t * 64 + frow;
    e = e < N_EDGES ? e : (N_EDGES - 1);
#pragma unroll
    for (int it = 0; it < 4; ++it)
      S[it] = *(const f32x4*)(efeat + (size_t)e * 128 + (fcb + it * 8) * 4);
  };
  auto write_ef = [&](char* buf) {
#pragma unroll
    for (int it = 0; it < 4; ++it) {
      bf16x4 v;
#pragma unroll
      for (int j = 0; j < 4; ++j) v[j] = f2bf(S[it][j]);
      *(bf16x4*)(buf + frow * 256 + (((fcb + it * 8) * 8) ^ fswz)) = v;
    }
  };
  int idxN[4];
  auto load_idx = [&](int t, int* ix) {
#pragma unroll
    for (int i = 0; i < 4; ++i) {
      int e = t * 64 + grow[i];
      e = e < N_EDGES ? e : (N_EDGES - 1);
      ix[i] = gseg[i] ? dst[e] : src[e];
    }
  };
  auto issue_g = [&](char* buf, const int* ix) {
#pragma unroll
    for (int i = 0; i < 4; ++i)
      gload16((const char*)nbf + (size_t)ix[i] * 256 + goff[i],
              buf + 16384 + w * 4096 + i * 1024);
  };

  // ---- prologue ----
  const int t0 = blockIdx.x;
  char* cur = smem;
  char* nxt = smem + 49152;
  {
    int ix0[4];
    load_idx(t0, ix0);
    stage_S(t0);
    write_ef(cur);
    issue_g(cur, ix0);
    load_idx(t0 + GRID, idxN);
  }

  for (int t = t0; t < NT; t += GRID) {
    stage_S(t + GRID);   // ef(t+1) -> regs (hidden across whole tile)
    issue_g(nxt, idxN);  // gathers(t+1) -> nxt
    bar_vm8();           // A: cur ready; fresh 8 loads stay in flight
    load_idx(t + 2 * GRID, idxN);

    // ---- GEMM1: K=384, rows wm*32..+32 from cur ----
    f32x4 acc[2][2];
#pragma unroll
    for (int m = 0; m < 2; ++m)
#pragma unroll
      for (int n = 0; n < 2; ++n) acc[m][n] = (f32x4)0.f;
#pragma unroll
    for (int ks = 0; ks < 12; ++ks) {
      bf16x8 a[2];
#pragma unroll
      for (int m = 0; m < 2; ++m) {
        int row = wm * 32 + m * 16 + lrow;
        int sw = (row & 15) << 4;
        a[m] = (ks < 4)
                   ? *(const bf16x8*)(cur + row * 256 + ((ks * 64 + kgrp * 16) ^ sw))
                   : *(const bf16x8*)(cur + 16384 + row * 512 +
                                      (((ks - 4) * 64 + kgrp * 16) ^ sw));
      }
#pragma unroll
      for (int m = 0; m < 2; ++m)
#pragma unroll
        for (int n = 0; n < 2; ++n)
          acc[m][n] = __builtin_amdgcn_mfma_f32_16x16x32_bf16(a[m], B1[ks][n],
                                                              acc[m][n], 0, 0, 0);
    }

    // ---- bias1 + SiLU -> Hb (rows wm*32.., cols wn*32..) ----
#pragma unroll
    for (int m = 0; m < 2; ++m)
#pragma unroll
      for (int n = 0; n < 2; ++n)
#pragma unroll
        for (int r = 0; r < 4; ++r) {
          float x = acc[m][n][r] + b1v[n];
          float h = x / (1.f + __expf(-x));
          int row = wm * 32 + m * 16 + kgrp * 4 + r;
          int col = wn * 32 + n * 16 + lrow;
          *(short*)(Hb + row * 256 + ((col * 2) ^ ((row & 15) << 4))) = f2bf(h);
        }
    bar_lds();  // C: H visible (gathers stay in flight)

    // ---- GEMM2: K=128 from Hb ----
    f32x4 acc2[2][2];
#pragma unroll
    for (int m = 0; m < 2; ++m)
#pragma unroll
      for (int n = 0; n < 2; ++n) acc2[m][n] = (f32x4)0.f;
#pragma unroll
    for (int ks = 0; ks < 4; ++ks) {
      bf16x8 a[2];
#pragma unroll
      for (int m = 0; m < 2; ++m) {
        int row = wm * 32 + m * 16 + lrow;
        a[m] = *(const bf16x8*)(Hb + row * 256 +
                                ((ks * 64 + kgrp * 16) ^ ((row & 15) << 4)));
      }
#pragma unroll
      for (int m = 0; m < 2; ++m)
#pragma unroll
        for (int n = 0; n < 2; ++n)
          acc2[m][n] = __builtin_amdgcn_mfma_f32_16x16x32_bf16(a[m], B2[ks][n],
                                                               acc2[m][n], 0, 0, 0);
    }

    // ---- x = acc2 + b2 -> xb ----
#pragma unroll
    for (int m = 0; m < 2; ++m)
#pragma unroll
      for (int n = 0; n < 2; ++n)
#pragma unroll
        for (int r = 0; r < 4; ++r) {
          float x = acc2[m][n][r] + b2v[n];
          int row = wm * 32 + m * 16 + kgrp * 4 + r;
          int col = wn * 32 + n * 16 + lrow;
          *(short*)(xb + row * 256 + ((col * 2) ^ ((row & 15) << 4))) = f2bf(x);
        }
    bar_lds();  // D: x visible (all H reads complete)

    // ---- fused LN (8 thr/row, 6 shuffles) + residual + coalesced store ----
    {
      bf16x4 xv[4];
      float s1 = 0.f, s2 = 0.f;
#pragma unroll
      for (int it = 0; it < 4; ++it) {
        int c4 = fcb + it * 8;
        xv[it] = *(const bf16x4*)(xb + frow * 256 + ((c4 * 8) ^ fswz));
#pragma unroll
        for (int j = 0; j < 4; ++j) {
          float f = bf2f(xv[it][j]);
          s1 += f;
          s2 += f * f;
        }
      }
      s1 += __shfl_xor(s1, 1, 64); s2 += __shfl_xor(s2, 1, 64);
      s1 += __shfl_xor(s1, 2, 64); s2 += __shfl_xor(s2, 2, 64);
      s1 += __shfl_xor(s1, 4, 64); s2 += __shfl_xor(s2, 4, 64);
      float mu = s1 * (1.f / 128.f);
      float var = s2 * (1.f / 128.f) - mu * mu;
      float rs = rsqrtf(var + LN_EPS);
      int e = t * 64 + frow;
      if (e < N_EDGES) {
        float* op = out + (size_t)e * 128;
#pragma unroll
        for (int it = 0; it < 4; ++it) {
          int c4 = fcb + it * 8;
          bf16x4 rv = *(const bf16x4*)(cur + frow * 256 + ((c4 * 8) ^ fswz));
          f32x4 g = *(const f32x4*)(gb + c4 * 4);
          f32x4 be = *(const f32x4*)(gb + 128 + c4 * 4);
          f32x4 o;
#pragma unroll
          for (int j = 0; j < 4; ++j)
            o[j] = (bf2f(xv[it][j]) - mu) * rs * g[j] + be[j] + bf2f(rv[j]);
          *(f32x4*)(op + c4 * 4) = o;
        }
      }
    }
    write_ef(nxt);  // ef(t+1); visible at A(t+1) via lgkm drain
    char* tmp = cur; cur = nxt; nxt = tmp;
  }
  asm volatile("s_waitcnt vmcnt(0)" ::: "memory");
}

// ---- fallback (tiny ws): block-per-edge, fp32 ----
__global__ void edge_simple(const float* __restrict__ efeat, const float* __restrict__ nfeat,
                            const int* __restrict__ src, const int* __restrict__ dst,
                            const float* __restrict__ W1, const float* __restrict__ b1,
                            const float* __restrict__ W2, const float* __restrict__ b2,
                            const float* __restrict__ g, const float* __restrict__ be,
                            float* __restrict__ out) {
  int e = blockIdx.x, j = threadIdx.x;
  __shared__ float cat[384], h[128], red[128];
  cat[j] = efeat[(size_t)e * 128 + j];
  cat[128 + j] = nfeat[(size_t)src[e] * 128 + j];
  cat[256 + j] = nfeat[(size_t)dst[e] * 128 + j];
  __syncthreads();
  float s = b1[j];
  for (int k = 0; k < 384; ++k) s += cat[k] * W1[k * 128 + j];
  h[j] = s / (1.f + expf(-s));
  __syncthreads();
  float o = b2[j];
  for (int k = 0; k < 128; ++k) o += h[k] * W2[k * 128 + j];
  red[j] = o;
  __syncthreads();
  __shared__ float mu, rs;
  if (j == 0) {
    float s1 = 0, s2 = 0;
    for (int k = 0; k < 128; ++k) { s1 += red[k]; s2 += red[k] * red[k]; }
    mu = s1 / 128.f;
    rs = rsqrtf(s2 / 128.f - mu * mu + LN_EPS);
  }
  __syncthreads();
  out[(size_t)e * 128 + j] = (o - mu) * rs * g[j] + be[j] + efeat[(size_t)e * 128 + j];
}

extern "C" void kernel_launch(void* const* d_in, const int* in_sizes, int n_in,
                              void* d_out, int out_size, void* d_ws, size_t ws_size,
                              hipStream_t stream) {
  const float* efeat = (const float*)d_in[0];
  const float* nfeat = (const float*)d_in[1];
  const int* src = (const int*)d_in[2];
  const int* dst = (const int*)d_in[3];
  const float* W1 = (const float*)d_in[4];
  const float* b1 = (const float*)d_in[5];
  const float* W2 = (const float*)d_in[6];
  const float* b2 = (const float*)d_in[7];
  const float* gamma = (const float*)d_in[8];
  const float* beta = (const float*)d_in[9];
  float* out = (float*)d_out;

  short* w1t = (short*)d_ws;         // 96 KB
  short* w2t = w1t + 384 * 128;      // 32 KB
  short* nbf = w2t + 128 * 128;      // 12.8 MB
  const size_t need =
      (size_t)(384 * 128 + 128 * 128 + (size_t)N_NODES * 128) * sizeof(short);

  if (ws_size >= need) {
    convert_kernel<<<1024, 256, 0, stream>>>(W1, W2, nfeat, w1t, w2t, nbf,
                                             out + (size_t)N_EDGES * 128);
    edge_mlp_pipelined<<<GRID, 512, 0, stream>>>(efeat, nbf, src, dst, w1t, w2t,
                                                 b1, b2, gamma, beta, out);
  } else {
    hipMemcpyAsync(out + (size_t)N_EDGES * 128, nfeat,
                   (size_t)N_NODES * 128 * sizeof(float),
                   hipMemcpyDeviceToDevice, stream);
    edge_simple<<<N_EDGES, 128, 0, stream>>>(efeat, nfeat, src, dst, W1, b1, W2,
                                             b2, gamma, beta, out);
  }
}